// Round 12
// baseline (716.068 us; speedup 1.0000x reference)
//
#include <hip/hip_runtime.h>

typedef unsigned short us;
typedef us us4 __attribute__((ext_vector_type(4)));
typedef us us8 __attribute__((ext_vector_type(8)));
typedef short bf16x8 __attribute__((ext_vector_type(8)));
typedef float f32x4 __attribute__((ext_vector_type(4)));

#define DEVI static __device__ __forceinline__

// constants for this problem instance
#define BB 16
#define NN 4096
#define PP 256
#define CC 8
#define MM (BB * NN)   // 65536

DEVI float bf2f(us u) { unsigned x = ((unsigned)u) << 16; return __builtin_bit_cast(float, x); }
DEVI us f2bf(float f) {
  unsigned x = __builtin_bit_cast(unsigned, f);
  x += 0x7fffu + ((x >> 16) & 1u);   // round to nearest even
  return (us)(x >> 16);
}

DEVI void gload_lds16(const void* g, void* l) {
  __builtin_amdgcn_global_load_lds(
      (const __attribute__((address_space(1))) void*)g,
      (__attribute__((address_space(3))) void*)l, 16, 0, 0);
}

DEVI float sigf(float x) { return 1.f / (1.f + __expf(-x)); }
DEVI float tanhfast(float a) {
  float aa = fabsf(a);
  float t = 1.f - 2.f / (1.f + __expf(2.f * aa));
  return copysignf(t, a);
}

DEVI void raw_barrier() {
  __builtin_amdgcn_sched_barrier(0);
  __builtin_amdgcn_s_barrier();      // RAW barrier: no implicit vmcnt(0) drain
  __builtin_amdgcn_sched_barrier(0);
}

// ---------------- weight prep: fp32 -> bf16, concatenated / gate-interleaved ----
// Wg layout (shuffle-free): row R -> J16 = R>>6, gate g = (R>>4)&3, c = R&15,
// output col j = J16*16 + c. Over K=512 ([h | s]):
//   g=0 (r):  [W_ih_r | W_hh_r]   g=1 (z): [W_ih_z | W_hh_z]
//   g=2 (xn): [W_ih_n | 0]        g=3 (hn): [0 | W_hh_n]
__global__ void k_prep(const float* __restrict__ Wres,
                       const float* __restrict__ Wpar, const float* __restrict__ bpar,
                       const float* __restrict__ Wnbr, const float* __restrict__ bnbr,
                       const float* __restrict__ Wih, const float* __restrict__ Whh,
                       const float* __restrict__ bih, const float* __restrict__ bhh,
                       us* __restrict__ Wr, us* __restrict__ Wcat, float* __restrict__ bcat,
                       us* __restrict__ Wg, float* __restrict__ bg) {
  int tid = blockIdx.x * blockDim.x + threadIdx.x;
  int nth = gridDim.x * blockDim.x;
  for (int i = tid; i < 256 * 256; i += nth) Wr[i] = f2bf(Wres[i]);
  for (int i = tid; i < 256 * 512; i += nth) {
    int o = i >> 9, k = i & 511;
    float v = (k < 256) ? Wpar[o * 256 + k] : Wnbr[o * 256 + (k - 256)];
    Wcat[i] = f2bf(v);
  }
  for (int i = tid; i < 256; i += nth) bcat[i] = bpar[i] + bnbr[i];
  for (int i = tid; i < 1024 * 512; i += nth) {
    int R = i >> 9, k = i & 511;
    int g = (R >> 4) & 3, j = ((R >> 6) << 4) + (R & 15);
    float v = 0.f;
    if (g == 0)      v = (k < 256) ? Wih[j * 256 + k]         : Whh[j * 256 + (k - 256)];
    else if (g == 1) v = (k < 256) ? Wih[(256 + j) * 256 + k] : Whh[(256 + j) * 256 + (k - 256)];
    else if (g == 2) v = (k < 256) ? Wih[(512 + j) * 256 + k] : 0.f;
    else             v = (k < 256) ? 0.f                      : Whh[(512 + j) * 256 + (k - 256)];
    Wg[i] = f2bf(v);
  }
  for (int i = tid; i < 1024; i += nth) {
    int g = (i >> 4) & 3, j = ((i >> 6) << 4) + (i & 15);
    float v;
    if (g == 0)      v = bih[j] + bhh[j];
    else if (g == 1) v = bih[256 + j] + bhh[256 + j];
    else if (g == 2) v = bih[512 + j];
    else             v = bhh[512 + j];
    bg[i] = v;
  }
}

// ---------------- x fp32 -> bf16 (vectorized) ----------------
__global__ __launch_bounds__(256) void k_f2bf(const float* __restrict__ x,
                                              us* __restrict__ o, int n8) {
  int i = blockIdx.x * blockDim.x + threadIdx.x;
  if (i >= n8) return;
  const float4* p = (const float4*)x + (size_t)i * 2;
  float4 a = p[0], b = p[1];
  us8 r;
  r[0] = f2bf(a.x); r[1] = f2bf(a.y); r[2] = f2bf(a.z); r[3] = f2bf(a.w);
  r[4] = f2bf(b.x); r[5] = f2bf(b.y); r[6] = f2bf(b.z); r[7] = f2bf(b.w);
  *(us8*)(o + (size_t)i * 8) = r;
}

// ---------------- children-avg: nbr[m] = avg(h[children(m)]) (bf16) ------------
__global__ __launch_bounds__(256)
void k_child(const us* __restrict__ h, const int* __restrict__ chd,
             const int* __restrict__ cnt, us* __restrict__ nbr) {
  int wid = (blockIdx.x * blockDim.x + threadIdx.x) >> 6;  // one wave per node
  int l = threadIdx.x & 63;
  int m = wid;                       // 0..MM-1
  int b = m >> 12;                   // N = 4096
  int c = cnt[m];
  float inv = 1.f / (float)c;
  const int* ch = chd + (size_t)m * CC;
  us4 cv[CC];
#pragma unroll
  for (int i = 0; i < CC; ++i) {
    int rowC = (b << 12) + ch[i];
    cv[i] = *((const us4*)(h + ((size_t)rowC << 8)) + l);
  }
  float a0 = 0.f, a1 = 0.f, a2 = 0.f, a3 = 0.f;
#pragma unroll
  for (int i = 0; i < CC; ++i) {
    float wgt = (i < c) ? 1.f : 0.f;
    a0 += wgt * bf2f(cv[i][0]); a1 += wgt * bf2f(cv[i][1]);
    a2 += wgt * bf2f(cv[i][2]); a3 += wgt * bf2f(cv[i][3]);
  }
  us4 nb;
  nb[0] = f2bf(a0 * inv); nb[1] = f2bf(a1 * inv);
  nb[2] = f2bf(a2 * inv); nb[3] = f2bf(a3 * inv);
  *((us4*)(nbr + ((size_t)m << 8)) + l) = nb;
}

// ---------------- B fragments: global(L2-hot) -> VGPR, MFMA layout -------------
template <int M4>
DEVI void loadBr(const us* __restrict__ Bw, int rowBase, int l, int kt, int KT,
                 bf16x8 (&b)[2][4]) {
#pragma unroll
  for (int ks = 0; ks < 2; ++ks)
#pragma unroll
    for (int j = 0; j < 4; ++j)
      if (M4 & (1 << j)) {
        int row = rowBase + j * 16 + (l & 15);
        b[ks][j] = *(const bf16x8*)(Bw + (size_t)row * KT + kt + ks * 32 + ((l >> 4) * 8));
      }
}

// ---------------- MFMA K-tile: A (256 rows) from LDS (swizzled), B from regs ---
template <int M4>
DEVI void mma8r(const us* As, int wr, int l, const bf16x8 (&b)[2][4],
                f32x4 (&acc)[8][4]) {
#pragma unroll
  for (int ks = 0; ks < 2; ++ks) {
    bf16x8 af[8];
#pragma unroll
    for (int i = 0; i < 8; ++i) {
      int row = wr * 128 + i * 16 + (l & 15);
      int kb = ((ks * 32 + (l >> 4) * 8) * 2) ^ ((row & 7) << 4);  // swizzled read
      af[i] = *(const bf16x8*)((const char*)As + row * 128 + kb);
    }
#pragma unroll
    for (int i = 0; i < 8; ++i)
#pragma unroll
      for (int j = 0; j < 4; ++j)
        if (M4 & (1 << j))
          acc[i][j] = __builtin_amdgcn_mfma_f32_16x16x32_bf16(af[i], b[ks][j], acc[i][j], 0, 0, 0);
  }
}

// ---------------- FUSED per-iteration kernel: s-GEMM + GRU-gates GEMM ----------
// R12: EPI1+EPI2 fused; s never leaves the CU as an operand.
// Phase 1: s = [h[par]|nbr] @ Wcat^T + bcat. A staged (GA gather, dbuf in
//   s_lds[0..1]); B=Wcat via regs. Epilogue: sF (f32, global scratch = d_out,
//   bit-identical to split version) + s bf16 -> LDS in staged-tile layout.
// Phase 2: gates = [h|s] @ Wg^T over 4 n-subtiles. s k-tiles (4 of 8) read
//   A-frags straight from resident LDS — NO staging, NO barriers. h k-tiles
//   stage into single 32 KB buffer; each stage's latency hides under the
//   preceding barrier-free s-tile MFMA block. B=Wg via regs (R8-proven).
// LDS: 4x32 KB s + 32 KB hbuf = 160 KB (static 160 KB proven in R11).
// NOTE: never request >2 waves/SIMD — acc is 128 regs (R2: spill, 3x slow).
template <int FINAL>
__global__ __launch_bounds__(512, 2)
void k_fused(const us* __restrict__ h, const us* __restrict__ nbr,
             const int* __restrict__ par,
             const us* __restrict__ Wcat, const float* __restrict__ bcat,
             const us* __restrict__ Wg, const float* __restrict__ bg,
             us* __restrict__ outBf, float* __restrict__ outF,
             float* __restrict__ sF) {
  __shared__ __align__(16) us s_lds[4][256 * 64];  // 128 KB ([0],[1] = phase-1 dbuf)
  __shared__ __align__(16) us hbuf[256 * 64];      //  32 KB
  int tid = threadIdx.x;
  int w = tid >> 6, l = tid & 63;
  int wr = w >> 2, wc = w & 3;
  int bid = blockIdx.x;
  int per = gridDim.x >> 3;
  int mi = (bid & 7) * per + (bid >> 3);           // XCD-chunked
  int mBase = mi * 256;
  f32x4 acc[8][4] = {};

  // gathered parent row per phase-1 staging row
  int prow[4];
  {
    int bb = (mBase >> 12) << 12;
#pragma unroll
    for (int c = 0; c < 4; ++c)
      prow[c] = bb + par[mBase + c * 64 + (tid >> 3)];
  }

  auto stage1 = [&](int t) {          // A=[h[par] | nbr], k-tile t -> s_lds[t&1]
    int kt = t * 64, buf = t & 1;
#pragma unroll
    for (int c = 0; c < 4; ++c) {
      int row = c * 64 + (tid >> 3);
      int kb = ((tid & 7) * 16) ^ ((row & 7) << 4);
      const char* ga;
      if (kt < 256) ga = (const char*)(h + (size_t)prow[c] * 256 + kt) + kb;
      else          ga = (const char*)(nbr + (size_t)(mBase + row) * 256 + (kt - 256)) + kb;
      gload_lds16(ga, (char*)s_lds[buf] + row * 128 + (tid & 7) * 16);
    }
  };
  auto stageH = [&](int q) {          // A=h (non-gathered), k-tile q -> hbuf
    int kt = q * 64;
#pragma unroll
    for (int c = 0; c < 4; ++c) {
      int row = c * 64 + (tid >> 3);
      int kb = ((tid & 7) * 16) ^ ((row & 7) << 4);
      const char* ga = (const char*)(h + (size_t)(mBase + row) * 256 + kt) + kb;
      gload_lds16(ga, (char*)hbuf + row * 128 + (tid & 7) * 16);
    }
  };

  // ---- phase 1: s-GEMM ----
  bf16x8 bfr[2][4];
  stage1(0);
#pragma unroll
  for (int t = 0; t < 8; ++t) {
    loadBr<0b1111>(Wcat, wc * 64, l, t * 64, 512, bfr);
    if (t < 7) {
      stage1(t + 1);
      asm volatile("s_waitcnt vmcnt(4)" ::: "memory");  // A(t)+B(t) done; A(t+1) in flight
    } else {
      asm volatile("s_waitcnt vmcnt(0)" ::: "memory");
    }
    raw_barrier();
    mma8r<0b1111>(s_lds[t & 1], wr, l, bfr, acc);
    raw_barrier();
  }

  stageH(0);   // prefetch first gates h-tile; latency hides under epilogue-1

  // ---- epilogue 1: sF (f32 global) + s (bf16 -> LDS, staged layout, buf wc) ---
#pragma unroll
  for (int i = 0; i < 8; ++i)
#pragma unroll
    for (int j = 0; j < 4; ++j) {
      int col = wc * 64 + j * 16 + (l & 15);
      int row0 = wr * 128 + i * 16 + ((l >> 4) << 2);
      float bb2 = bcat[col];
#pragma unroll
      for (int e = 0; e < 4; ++e) {
        float v = acc[i][j][e] + bb2;
        int row = row0 + e;
        sF[(size_t)(mBase + row) * 256 + col] = v;
        int byte = ((j * 16 + (l & 15)) * 2) ^ ((row & 7) << 4);
        *(us*)((char*)s_lds[wc] + row * 128 + byte) = f2bf(v);
      }
    }
  // boundary: s ds_writes + sF stores visible; hbuf(0) staged
  asm volatile("s_waitcnt vmcnt(0) lgkmcnt(0)" ::: "memory");
  raw_barrier();

  // ---- phase 2: gates over 4 n-subtiles ----
#pragma unroll
  for (int nt = 0; nt < 4; ++nt) {
#pragma unroll
    for (int i = 0; i < 8; ++i)
#pragma unroll
      for (int j = 0; j < 4; ++j) acc[i][j] = f32x4{0.f, 0.f, 0.f, 0.f};
    int rowB = (nt * 4 + wc) * 64;   // this wave's Wg gate-row block
#pragma unroll
    for (int q = 0; q < 4; ++q) {
      bf16x8 bh[2][4], bs[2][4];
      loadBr<0b0111>(Wg, rowB, l, q * 64, 512, bh);        // h-half weights
      loadBr<0b1011>(Wg, rowB, l, 256 + q * 64, 512, bs);  // s-half weights
      mma8r<0b1011>(s_lds[q], wr, l, bs, acc);   // s-part: resident LDS, no barrier
      asm volatile("s_waitcnt vmcnt(0)" ::: "memory");     // h stage + bh landed
      raw_barrier();                             // hbuf(q) visible
      mma8r<0b0111>(hbuf, wr, l, bh, acc);       // h-part
      raw_barrier();                             // hbuf reads done before restage
      if (q < 3)           stageH(q + 1);
      else if (nt < 3)     stageH(0);
    }
    // ---- epilogue 2 (subtile nt): GRU gates + blend with sv (f32 from sF) ----
    int outCol = (nt * 4 + wc) * 16 + (l & 15);
    float b0 = bg[rowB + 0  + (l & 15)];
    float b1 = bg[rowB + 16 + (l & 15)];
    float b2 = bg[rowB + 32 + (l & 15)];
    float b3 = bg[rowB + 48 + (l & 15)];
#pragma unroll
    for (int i = 0; i < 8; ++i) {
      int row0 = mBase + wr * 128 + i * 16 + ((l >> 4) << 2);
#pragma unroll
      for (int e = 0; e < 4; ++e) {
        float r = sigf(acc[i][0][e] + b0);
        float z = sigf(acc[i][1][e] + b1);
        float n = tanhfast(acc[i][2][e] + b2 + r * (acc[i][3][e] + b3));
        size_t off = (size_t)(row0 + e) * 256 + outCol;
        float sv = __hip_atomic_load(&sF[off], __ATOMIC_RELAXED,
                                     __HIP_MEMORY_SCOPE_AGENT);  // L1-bypass
        float o = (1.f - z) * n + z * sv;
        if (FINAL) outF[off] = o;
        else       outBf[off] = f2bf(o);
      }
    }
  }
}

// ---------------- standalone GEMM (resize only), R11 core ----------------------
template <int EPI, int KTOT, int KSPLIT, int NT, bool GA>
__global__ __launch_bounds__(512, 2)
void k_gemm(const us* __restrict__ A0, const us* __restrict__ A1, int strideA,
            const us* __restrict__ Bw, const float* __restrict__ bias,
            us* __restrict__ outBf, float* __restrict__ outF,
            const float* __restrict__ sF, int writeF32,
            const int* __restrict__ par) {
  __shared__ __align__(16) us As[2][256 * 64];
  __shared__ __align__(16) us Bs[2][256 * 64];
  int tid = threadIdx.x;
  int w = tid >> 6, l = tid & 63;
  int wr = w >> 2, wc = w & 3;
  int bid = blockIdx.x;
  int per = gridDim.x >> 3;
  int g = (bid & 7) * per + (bid >> 3);
  int mi, ni;
  if (NT == 1) { mi = g; ni = 0; }
  else         { mi = g / NT; ni = g - mi * NT; }
  int mBase = mi * 256, nBase = ni * 256;
  f32x4 acc[8][4] = {};

  auto stage = [&](int t) {
    int kt = t * 64, buf = t & 1;
    const us* aSrc; int kOff;
    if (kt < KSPLIT) { aSrc = A0; kOff = kt; }
    else             { aSrc = A1; kOff = kt - KSPLIT; }
#pragma unroll
    for (int c = 0; c < 4; ++c) {
      int row = c * 64 + (tid >> 3);
      int kb = ((tid & 7) * 16) ^ ((row & 7) << 4);
      const char* ga = (const char*)(aSrc + (size_t)(mBase + row) * strideA + kOff) + kb;
      gload_lds16(ga, (char*)As[buf] + row * 128 + (tid & 7) * 16);
      const char* gb = (const char*)(Bw + (size_t)(nBase + row) * KTOT + kt) + kb;
      gload_lds16(gb, (char*)Bs[buf] + row * 128 + (tid & 7) * 16);
    }
  };

  constexpr int NKT = KTOT / 64;
  stage(0);
#pragma unroll
  for (int t = 0; t < NKT; ++t) {
    if (t + 1 < NKT) {
      stage(t + 1);
      asm volatile("s_waitcnt vmcnt(8)" ::: "memory");
    } else {
      asm volatile("s_waitcnt vmcnt(0)" ::: "memory");
    }
    raw_barrier();
    int buf = t & 1;
    {
      bf16x8 af[8], bfr2[4];
#pragma unroll
      for (int ks = 0; ks < 2; ++ks) {
#pragma unroll
        for (int i = 0; i < 8; ++i) {
          int row = wr * 128 + i * 16 + (l & 15);
          int kb = ((ks * 32 + (l >> 4) * 8) * 2) ^ ((row & 7) << 4);
          af[i] = *(const bf16x8*)((const char*)As[buf] + row * 128 + kb);
        }
#pragma unroll
        for (int j = 0; j < 4; ++j) {
          int row = wc * 64 + j * 16 + (l & 15);
          int kb = ((ks * 32 + (l >> 4) * 8) * 2) ^ ((row & 7) << 4);
          bfr2[j] = *(const bf16x8*)((const char*)Bs[buf] + row * 128 + kb);
        }
#pragma unroll
        for (int i = 0; i < 8; ++i)
#pragma unroll
          for (int j = 0; j < 4; ++j)
            acc[i][j] = __builtin_amdgcn_mfma_f32_16x16x32_bf16(af[i], bfr2[j], acc[i][j], 0, 0, 0);
      }
    }
    raw_barrier();
  }

  int rBase0 = mBase + wr * 128;
  int cBase0 = nBase + wc * 64;
#pragma unroll
  for (int i = 0; i < 8; ++i)
#pragma unroll
    for (int j = 0; j < 4; ++j) {
      int col = cBase0 + j * 16 + (l & 15);
      int row0 = rBase0 + i * 16 + ((l >> 4) << 2);
      float bb = bias[col];
#pragma unroll
      for (int e = 0; e < 4; ++e) {
        float v = acc[i][j][e] + bb;
        size_t off = (size_t)(row0 + e) * 256 + col;
        outBf[off] = f2bf(v);
        if (EPI == 1) outF[off] = v;
      }
    }
}

extern "C" void kernel_launch(void* const* d_in, const int* in_sizes, int n_in,
                              void* d_out, int out_size, void* d_ws, size_t ws_size,
                              hipStream_t stream) {
  const float* x    = (const float*)d_in[0];
  const int*   par  = (const int*)d_in[1];
  const int*   chd  = (const int*)d_in[2];
  const int*   cnt  = (const int*)d_in[3];
  const float* Wres = (const float*)d_in[4];
  const float* bres = (const float*)d_in[5];
  const float* Wpar = (const float*)d_in[6];
  const float* bpar = (const float*)d_in[7];
  const float* Wnbr = (const float*)d_in[8];
  const float* bnbr = (const float*)d_in[9];
  const float* Wih  = (const float*)d_in[10];
  const float* Whh  = (const float*)d_in[11];
  const float* bih  = (const float*)d_in[12];
  const float* bhh  = (const float*)d_in[13];

  char* ws = (char*)d_ws;
  size_t off = 0;
  auto alloc = [&](size_t sz) { char* p = ws + off; off += (sz + 255) & ~(size_t)255; return p; };
  us*    Wg   = (us*)alloc((size_t)1024 * 512 * 2);
  us*    Wcat = (us*)alloc((size_t)256 * 512 * 2);
  us*    Wr   = (us*)alloc((size_t)256 * 256 * 2);
  float* bcat = (float*)alloc(256 * 4);
  float* bg   = (float*)alloc(1024 * 4);
  us*    xbf  = (us*)alloc((size_t)MM * 256 * 2);
  us*    h0   = (us*)alloc((size_t)MM * 256 * 2);
  us*    h1   = (us*)alloc((size_t)MM * 256 * 2);
  us*    nbr  = (us*)alloc((size_t)MM * 256 * 2);
  float* sF   = (float*)d_out;  // f32 s scratch lives in d_out (final iter
                                // overwrites each slot after its own sv read)

  k_prep<<<256, 256, 0, stream>>>(Wres, Wpar, bpar, Wnbr, bnbr, Wih, Whh, bih, bhh,
                                  Wr, Wcat, bcat, Wg, bg);
  k_f2bf<<<(MM * 256 / 8) / 256, 256, 0, stream>>>(x, xbf, MM * 256 / 8);

  // h0 = x @ W_resize^T + b_resize
  k_gemm<0, 256, 256, 1, false><<<256, 512, 0, stream>>>(
      xbf, xbf, 256, Wr, bres, h0, nullptr, nullptr, 0, nullptr);

  us* hc = h0;
  for (int it = 0; it < 3; ++it) {
    us* hn = (hc == h0) ? h1 : h0;
    k_child<<<MM / 4, 256, 0, stream>>>(hc, chd, cnt, nbr);
    if (it < 2)
      k_fused<0><<<256, 512, 0, stream>>>(hc, nbr, par, Wcat, bcat, Wg, bg,
                                          hn, nullptr, sF);
    else
      k_fused<1><<<256, 512, 0, stream>>>(hc, nbr, par, Wcat, bcat, Wg, bg,
                                          nullptr, (float*)d_out, sF);
    hc = hn;
  }
}